// Round 13
// baseline (196.812 us; speedup 1.0000x reference)
//
#include <hip/hip_runtime.h>
#include <hip/hip_bf16.h>

#define D_MODEL 768
#define D_HIDDEN 2048
#define NHEADS 12
#define BATCH 4
#define SEQ 128
#define MROWS (BATCH*SEQ)                      // 512
#define SCORE_ELEMS (BATCH*NHEADS*SEQ*SEQ)     // 786432
#define REG_OFF SCORE_ELEMS
#define FIRES_OFF (SCORE_ELEMS + 1)
#define NROWS_T 65536                          // fires rows (b,q,k)
#define FIRES_WAVES 2048
#define FIRES_BLOCKS 512
#define SCORE_BLOCKS (BATCH*NHEADS*16)         // 768
#define REG_BLOCKS 512
#define TRIGCAP 64

typedef __attribute__((ext_vector_type(8))) short bf16x8;
typedef __attribute__((ext_vector_type(4))) float f32x4;

static __device__ __forceinline__ unsigned short f2bf(float f) {
    union { float f; unsigned u; } v; v.f = f;
    unsigned u = v.u;
    return (unsigned short)((u + 0x7FFFu + ((u >> 16) & 1u)) >> 16);  // RNE
}

static __device__ __forceinline__ void split_bf16(float v, short& hi, short& lo) {
    unsigned short h = f2bf(v);
    float hf = __uint_as_float((unsigned)h << 16);
    float lf = v - hf;
    hi = (short)h;
    lo = (short)f2bf(lf);
}

static __device__ __forceinline__ float fsqrt_fast(float x) {
    return __builtin_amdgcn_sqrtf(x);      // raw v_sqrt_f32 (reg_loss tol 2%)
}

// ---------------------------------------------------------------------------
// Kernel 1: encoder GEMM via SPLIT-BF16 MFMA + inline block-local fp64 fix.
// (unchanged from R10 -- proven). Block (0,0,0) zeroes out[REG_OFF].
// ---------------------------------------------------------------------------
__global__ __launch_bounds__(256) void enc_kernel(
    const float* __restrict__ x,
    const float* __restrict__ WQ, const float* __restrict__ WK,
    const float* __restrict__ bQ, const float* __restrict__ bK,
    float* __restrict__ qbuf, float* __restrict__ kbuf,
    float* __restrict__ out)
{
    __shared__ unsigned tcnt;
    __shared__ unsigned tlist[TRIGCAP];
    __shared__ double   redd[4];

    const int bufid = blockIdx.z;
    const float* W    = bufid ? WK : WQ;
    const float* bias = bufid ? bK : bQ;
    float* outbuf     = bufid ? kbuf : qbuf;

    const int t  = threadIdx.x;
    if (t == 0) tcnt = 0u;
    if (blockIdx.x == 0 && blockIdx.y == 0 && blockIdx.z == 0 && t == 0)
        out[REG_OFF] = 0.f;
    __syncthreads();

    const int w  = t >> 6;
    const int l  = t & 63;
    const int mt = blockIdx.y * 64 + (w >> 1) * 32;
    const int nt = blockIdx.x * 64 + (w & 1) * 32;
    const int lr = l & 15;
    const int hg = (l >> 4) * 8;

    f32x4 acc[2][2];
    #pragma unroll
    for (int i = 0; i < 2; ++i)
        #pragma unroll
        for (int j = 0; j < 2; ++j) { f32x4 z = {0.f, 0.f, 0.f, 0.f}; acc[i][j] = z; }

    for (int kk = 0; kk < D_MODEL; kk += 32) {
        const int h0 = kk + hg;
        bf16x8 ah[2], al[2], bh[2], bl[2];
        #pragma unroll
        for (int fi = 0; fi < 2; ++fi) {
            const float* xp = x + (size_t)(mt + fi * 16 + lr) * D_MODEL + h0;
            const float4 v1 = *reinterpret_cast<const float4*>(xp);
            const float4 v2 = *reinterpret_cast<const float4*>(xp + 4);
            const float vv[8] = {v1.x, v1.y, v1.z, v1.w, v2.x, v2.y, v2.z, v2.w};
            #pragma unroll
            for (int i = 0; i < 8; ++i) {
                short h_, lo_;
                split_bf16(vv[i], h_, lo_);
                ah[fi][i] = h_; al[fi][i] = lo_;
            }
        }
        #pragma unroll
        for (int fj = 0; fj < 2; ++fj) {
            const int col = nt + fj * 16 + lr;
            #pragma unroll
            for (int i = 0; i < 8; ++i) {
                short h_, lo_;
                split_bf16(W[(size_t)(h0 + i) * D_HIDDEN + col], h_, lo_);
                bh[fj][i] = h_; bl[fj][i] = lo_;
            }
        }
        #pragma unroll
        for (int fi = 0; fi < 2; ++fi)
            #pragma unroll
            for (int fj = 0; fj < 2; ++fj) {
                acc[fi][fj] = __builtin_amdgcn_mfma_f32_16x16x32_bf16(
                    ah[fi], bh[fj], acc[fi][fj], 0, 0, 0);
                acc[fi][fj] = __builtin_amdgcn_mfma_f32_16x16x32_bf16(
                    ah[fi], bl[fj], acc[fi][fj], 0, 0, 0);
                acc[fi][fj] = __builtin_amdgcn_mfma_f32_16x16x32_bf16(
                    al[fi], bh[fj], acc[fi][fj], 0, 0, 0);
            }
    }

    #pragma unroll
    for (int fi = 0; fi < 2; ++fi)
        #pragma unroll
        for (int fj = 0; fj < 2; ++fj)
            #pragma unroll
            for (int j = 0; j < 4; ++j) {
                const int row = mt + fi * 16 + (l >> 4) * 4 + j;
                const int col = nt + fj * 16 + lr;
                float pre = acc[fi][fj][j] + bias[col];
                if (fabsf(pre) < 3e-4f) {
                    unsigned idx = atomicAdd(&tcnt, 1u);
                    if (idx < TRIGCAP) {
                        tlist[idx] = ((unsigned)row << 11) | (unsigned)col;
                    } else {
                        const float* xr = x + (size_t)row * D_MODEL;
                        const float* wc = W + col;
                        double s = (double)bias[col];
                        for (int dd = 0; dd < D_MODEL; ++dd)
                            s += (double)xr[dd] * (double)wc[(size_t)dd * D_HIDDEN];
                        pre = (float)s;
                    }
                }
                outbuf[(size_t)row * D_HIDDEN + col] = fmaxf(pre, 0.f);
            }

    __syncthreads();
    const unsigned n = min(tcnt, (unsigned)TRIGCAP);
    for (unsigned i = 0; i < n; ++i) {
        const unsigned e = tlist[i];
        const int hh = (int)(e & 2047u);
        const int mm = (int)(e >> 11);
        double s = 0.0;
        #pragma unroll
        for (int k = 0; k < 3; ++k) {
            const int dd = t + k * 256;
            s += (double)x[(size_t)mm * D_MODEL + dd]
               * (double)W[(size_t)dd * D_HIDDEN + hh];
        }
        #pragma unroll
        for (int off = 32; off > 0; off >>= 1) s += __shfl_down(s, off);
        if (l == 0) redd[w] = s;
        __syncthreads();
        if (t == 0) {
            double tot = redd[0] + redd[1] + redd[2] + redd[3] + (double)bias[hh];
            outbuf[(size_t)mm * D_HIDDEN + hh] = fmaxf((float)tot, 0.f);
        }
        __syncthreads();
    }
}

// ---------------------------------------------------------------------------
// Kernel 1c: sign masks. Row r: qmask[r*64+l] bit (4j+e) = q[r, 256j+4l+e]>0.
// 512 blocks x 128 threads (t<64: q, t>=64: k). All reads L2-hot.
// ---------------------------------------------------------------------------
__global__ __launch_bounds__(128) void mask_kernel(
    const float* __restrict__ qbuf, const float* __restrict__ kbuf,
    unsigned* __restrict__ qmask, unsigned* __restrict__ kmask)
{
    const int r = blockIdx.x;
    const int t = threadIdx.x;
    const int l = t & 63;
    const float* src = (t < 64) ? qbuf : kbuf;
    unsigned* dst    = (t < 64) ? qmask : kmask;
    unsigned m = 0;
    #pragma unroll
    for (int j = 0; j < 8; ++j)
        #pragma unroll
        for (int e = 0; e < 4; ++e) {
            const float v = src[(size_t)r * D_HIDDEN + 256 * j + 4 * l + e];
            m |= (v > 0.f ? 1u : 0u) << (4 * j + e);
        }
    dst[r * 64 + l] = m;
}

// ---------------------------------------------------------------------------
// Kernel 2: fires [0,512) + score [512,1280) + reg [1280,1792).
//
// Fires = FILL-CLONE: dense moving front, per step one dword mask load per
// lane + ~10 VALU bit-expands per 16 elems + plain cached f32x4 stores.
// No values, no sqrt, no heavy reads. k-mask held 8 steps. -1-shifted
// aligned stores; 2 shfl/step neighbor bits; R==0 corner split to scalars.
//
// Reg role: 512 blocks, block = one q-row x all 128 k-rows, values from
// L2-resident q/k, quarter-rate sqrt VALU overlaps fires' store stalls.
// ---------------------------------------------------------------------------
__global__ __launch_bounds__(256) void main_kernel(
    const float* __restrict__ qbuf, const float* __restrict__ kbuf,
    const unsigned* __restrict__ qmask, const unsigned* __restrict__ kmask,
    const float* __restrict__ Wdec, const float* __restrict__ bdec,
    float* __restrict__ out)
{
    __shared__ float wcol[D_HIDDEN];
    __shared__ float red[4][64][16];
    __shared__ float rs[4];
    const int t  = threadIdx.x;
    const int bi = blockIdx.x;
    const int w  = t >> 6;
    const int l  = t & 63;

    if (bi < FIRES_BLOCKS) {
        // ------------------------------ fires ------------------------------
        const int g  = bi * 4 + w;                         // 0..2047
        const int g7 = g >> 7;                             // 0..15
        const int gk = g & 127;

        f32x4* out4 = reinterpret_cast<f32x4*>(out + FIRES_OFF - 1);

        #pragma unroll 1
        for (int b = 0; b < 4; ++b) {
            const unsigned km = kmask[(b * SEQ + gk) * 64 + l];

            #pragma unroll 1
            for (int ss = 0; ss < 8; ++ss) {
                const int s    = b * 8 + ss;
                const int R    = g + s * FIRES_WAVES;
                const int brow = s * 16 + g7;              // R >> 7
                const unsigned qm = qmask[brow * 64 + l];
                const unsigned m   = qm & km;
                const unsigned mp  = __shfl_up(m, 1);
                const unsigned m63 = __shfl(m, 63);

                unsigned pb1 = 0;
                if (l == 0 && R > 0) {
                    const int pbrow = (R - 1) >> 7;
                    const int pb    = pbrow >> 7;
                    const int pkrow = (pb << 7) + ((R - 1) & 127);
                    pb1 = (qmask[pbrow * 64 + 63] >> 31)
                        & (kmask[pkrow * 64 + 63] >> 31) & 1u;
                }

                #pragma unroll
                for (int j = 0; j < 8; ++j) {
                    unsigned b0;
                    if (l == 0) b0 = (j == 0) ? pb1 : (m63 >> (4 * (j - 1) + 3)) & 1u;
                    else        b0 = (mp >> (4 * j + 3)) & 1u;
                    f32x4 f;
                    f[0] = b0 ? 1.f : 0.f;
                    f[1] = ((m >> (4 * j + 0)) & 1u) ? 1.f : 0.f;
                    f[2] = ((m >> (4 * j + 1)) & 1u) ? 1.f : 0.f;
                    f[3] = ((m >> (4 * j + 2)) & 1u) ? 1.f : 0.f;
                    if (R == 0 && j == 0 && l == 0) {
                        out[FIRES_OFF + 0] = f[1];
                        out[FIRES_OFF + 1] = f[2];
                        out[FIRES_OFF + 2] = f[3];
                    } else {
                        out4[(size_t)R * 512 + 64 * j + l] = f;
                    }
                }
            }
        }

        // global-last element (row 65535, h=2047)
        if (bi == FIRES_BLOCKS - 1 && w == 3 && l == 0) {
            const float pv = qbuf[(size_t)511 * D_HIDDEN + 2047]
                           * kbuf[(size_t)511 * D_HIDDEN + 2047];
            out[(size_t)(FIRES_OFF - 1) + (size_t)NROWS_T * D_HIDDEN] = (pv > 0.f) ? 1.f : 0.f;
        }
        return;
    }

    if (bi < FIRES_BLOCKS + SCORE_BLOCKS) {
        // ------------------------------ score ------------------------------
        const int sb  = bi - FIRES_BLOCKS;
        const int sub = sb & 15;
        const int pr  = sb >> 4;
        const int n   = pr % NHEADS;
        const int b   = pr / NHEADS;

        for (int idx = t; idx < D_HIDDEN; idx += 256)
            wcol[idx] = Wdec[(size_t)idx * NHEADS + n];
        __syncthreads();

        const int qt   = (sub >> 2) * 32;
        const int kt   = (sub & 3) * 32;
        const int lrow = l & 15;
        const int koff = (l >> 4) * 8;

        f32x4 acc[2][2];
        #pragma unroll
        for (int i = 0; i < 2; ++i)
            #pragma unroll
            for (int j = 0; j < 2; ++j) { f32x4 z = {0.f, 0.f, 0.f, 0.f}; acc[i][j] = z; }

        const float* qb = qbuf + (size_t)b * SEQ * D_HIDDEN;
        const float* kb = kbuf + (size_t)b * SEQ * D_HIDDEN;

        const int hlo = w * 512;
        for (int kk = hlo; kk < hlo + 512; kk += 32) {
            const int h0 = kk + koff;
            float wv[8];
            #pragma unroll
            for (int i = 0; i < 8; ++i) wv[i] = wcol[h0 + i];

            bf16x8 afrag[2], bfrag[2];
            #pragma unroll
            for (int fi = 0; fi < 2; ++fi) {
                const float* qp = qb + (size_t)(qt + fi * 16 + lrow) * D_HIDDEN + h0;
                const float4 q1 = *reinterpret_cast<const float4*>(qp);
                const float4 q2 = *reinterpret_cast<const float4*>(qp + 4);
                const float qf[8] = {q1.x, q1.y, q1.z, q1.w, q2.x, q2.y, q2.z, q2.w};
                #pragma unroll
                for (int i = 0; i < 8; ++i) afrag[fi][i] = (short)f2bf(qf[i] * wv[i]);
            }
            #pragma unroll
            for (int fj = 0; fj < 2; ++fj) {
                const float* kp = kb + (size_t)(kt + fj * 16 + lrow) * D_HIDDEN + h0;
                const float4 k1 = *reinterpret_cast<const float4*>(kp);
                const float4 k2 = *reinterpret_cast<const float4*>(kp + 4);
                const float kf[8] = {k1.x, k1.y, k1.z, k1.w, k2.x, k2.y, k2.z, k2.w};
                #pragma unroll
                for (int i = 0; i < 8; ++i) bfrag[fj][i] = (short)f2bf(kf[i]);
            }
            #pragma unroll
            for (int fi = 0; fi < 2; ++fi)
                #pragma unroll
                for (int fj = 0; fj < 2; ++fj)
                    acc[fi][fj] = __builtin_amdgcn_mfma_f32_16x16x32_bf16(
                        afrag[fi], bfrag[fj], acc[fi][fj], 0, 0, 0);
        }

        #pragma unroll
        for (int fi = 0; fi < 2; ++fi)
            #pragma unroll
            for (int fj = 0; fj < 2; ++fj)
                #pragma unroll
                for (int j = 0; j < 4; ++j)
                    red[w][l][fi * 8 + fj * 4 + j] = acc[fi][fj][j];
        __syncthreads();

        const float bd   = bdec[n];
        const int   outb = (b * NHEADS + n) * SEQ * SEQ;
        #pragma unroll
        for (int u = 0; u < 4; ++u) {
            const int j = w * 4 + u;
            const float s = (red[0][l][j] + red[1][l][j])
                          + (red[2][l][j] + red[3][l][j]);
            const int fi = j >> 3, fj = (j >> 2) & 1, jj = j & 3;
            const int row = qt + fi * 16 + (l >> 4) * 4 + jj;
            const int col = kt + fj * 16 + (l & 15);
            out[outb + row * SEQ + col] = s * 0.125f + bd;
        }
        return;
    }

    // -------------------------------- reg ---------------------------------
    {
        const int qr = bi - FIRES_BLOCKS - SCORE_BLOCKS;   // 0..511
        const int b  = qr >> 7;
        const float* qrow = qbuf + (size_t)qr * D_HIDDEN + t * 8;
        const f32x4 q1 = *reinterpret_cast<const f32x4*>(qrow);
        const f32x4 q2 = *reinterpret_cast<const f32x4*>(qrow + 4);

        float acc = 0.f;
        #pragma unroll 1
        for (int k = 0; k < SEQ; ++k) {
            const float* kp = kbuf + (size_t)(b * SEQ + k) * D_HIDDEN + t * 8;
            const f32x4 k1 = *reinterpret_cast<const f32x4*>(kp);
            const f32x4 k2 = *reinterpret_cast<const f32x4*>(kp + 4);
            float s = 0.f;
            #pragma unroll
            for (int e = 0; e < 4; ++e) s += fsqrt_fast(q1[e] * k1[e] + 1e-6f);
            #pragma unroll
            for (int e = 0; e < 4; ++e) s += fsqrt_fast(q2[e] * k2[e] + 1e-6f);
            acc += s;
        }

        #pragma unroll
        for (int off = 32; off > 0; off >>= 1) acc += __shfl_down(acc, off);
        if (l == 0) rs[w] = acc;
        __syncthreads();
        if (t == 0)
            atomicAdd(out + REG_OFF, ((rs[0] + rs[1]) + (rs[2] + rs[3])) * 1e-3f);
    }
}

// ---------------------------------------------------------------------------
extern "C" void kernel_launch(void* const* d_in, const int* in_sizes, int n_in,
                              void* d_out, int out_size, void* d_ws, size_t ws_size,
                              hipStream_t stream) {
    const float* x  = (const float*)d_in[0];
    const float* WQ = (const float*)d_in[1];
    const float* WK = (const float*)d_in[2];
    const float* bQ = (const float*)d_in[3];
    const float* bK = (const float*)d_in[4];
    const float* Wd = (const float*)d_in[5];
    const float* bd = (const float*)d_in[6];
    float* out  = (float*)d_out;
    float* qbuf = (float*)d_ws;                                // 4 MB
    float* kbuf = qbuf + (size_t)MROWS * D_HIDDEN;             // 4 MB
    unsigned* qmask = (unsigned*)(kbuf + (size_t)MROWS * D_HIDDEN);  // 128 KB
    unsigned* kmask = qmask + (size_t)MROWS * 64;                    // 128 KB

    dim3 b256(256);

    enc_kernel<<<dim3(D_HIDDEN / 64, MROWS / 64, 2), b256, 0, stream>>>(
        x, WQ, WK, bQ, bK, qbuf, kbuf, out);

    mask_kernel<<<dim3(MROWS), dim3(128), 0, stream>>>(qbuf, kbuf, qmask, kmask);

    main_kernel<<<dim3(FIRES_BLOCKS + SCORE_BLOCKS + REG_BLOCKS), b256, 0, stream>>>(
        qbuf, kbuf, qmask, kmask, Wd, bd, out);
}

// Round 14
// 171.298 us; speedup vs baseline: 1.1489x; 1.1489x over previous
//
#include <hip/hip_runtime.h>
#include <hip/hip_bf16.h>

#define D_MODEL 768
#define D_HIDDEN 2048
#define NHEADS 12
#define BATCH 4
#define SEQ 128
#define MROWS (BATCH*SEQ)                      // 512
#define SCORE_ELEMS (BATCH*NHEADS*SEQ*SEQ)     // 786432
#define REG_OFF SCORE_ELEMS
#define FIRES_OFF (SCORE_ELEMS + 1)
#define NROWS_T 65536                          // fires rows (b,q,k)
#define FIRES_WAVES 2048
#define FIRES_BLOCKS 512
#define SCORE_BLOCKS (BATCH*NHEADS*16)         // 768
#define TRIGCAP 64

typedef __attribute__((ext_vector_type(8))) short bf16x8;
typedef __attribute__((ext_vector_type(4))) float f32x4;

static __device__ __forceinline__ unsigned short f2bf(float f) {
    union { float f; unsigned u; } v; v.f = f;
    unsigned u = v.u;
    return (unsigned short)((u + 0x7FFFu + ((u >> 16) & 1u)) >> 16);  // RNE
}

static __device__ __forceinline__ void split_bf16(float v, short& hi, short& lo) {
    unsigned short h = f2bf(v);
    float hf = __uint_as_float((unsigned)h << 16);
    float lf = v - hf;
    hi = (short)h;
    lo = (short)f2bf(lf);
}

static __device__ __forceinline__ float fsqrt_fast(float x) {
    return __builtin_amdgcn_sqrtf(x);
}

// ---------------------------------------------------------------------------
// Kernel 1: encoder GEMM via SPLIT-BF16 MFMA + inline block-local fp64 fix.
// (unchanged from R10 -- proven.)
// ---------------------------------------------------------------------------
__global__ __launch_bounds__(256) void enc_kernel(
    const float* __restrict__ x,
    const float* __restrict__ WQ, const float* __restrict__ WK,
    const float* __restrict__ bQ, const float* __restrict__ bK,
    float* __restrict__ qbuf, float* __restrict__ kbuf)
{
    __shared__ unsigned tcnt;
    __shared__ unsigned tlist[TRIGCAP];
    __shared__ double   redd[4];

    const int bufid = blockIdx.z;
    const float* W    = bufid ? WK : WQ;
    const float* bias = bufid ? bK : bQ;
    float* outbuf     = bufid ? kbuf : qbuf;

    const int t  = threadIdx.x;
    if (t == 0) tcnt = 0u;
    __syncthreads();

    const int w  = t >> 6;
    const int l  = t & 63;
    const int mt = blockIdx.y * 64 + (w >> 1) * 32;
    const int nt = blockIdx.x * 64 + (w & 1) * 32;
    const int lr = l & 15;
    const int hg = (l >> 4) * 8;

    f32x4 acc[2][2];
    #pragma unroll
    for (int i = 0; i < 2; ++i)
        #pragma unroll
        for (int j = 0; j < 2; ++j) { f32x4 z = {0.f, 0.f, 0.f, 0.f}; acc[i][j] = z; }

    for (int kk = 0; kk < D_MODEL; kk += 32) {
        const int h0 = kk + hg;
        bf16x8 ah[2], al[2], bh[2], bl[2];
        #pragma unroll
        for (int fi = 0; fi < 2; ++fi) {
            const float* xp = x + (size_t)(mt + fi * 16 + lr) * D_MODEL + h0;
            const float4 v1 = *reinterpret_cast<const float4*>(xp);
            const float4 v2 = *reinterpret_cast<const float4*>(xp + 4);
            const float vv[8] = {v1.x, v1.y, v1.z, v1.w, v2.x, v2.y, v2.z, v2.w};
            #pragma unroll
            for (int i = 0; i < 8; ++i) {
                short h_, lo_;
                split_bf16(vv[i], h_, lo_);
                ah[fi][i] = h_; al[fi][i] = lo_;
            }
        }
        #pragma unroll
        for (int fj = 0; fj < 2; ++fj) {
            const int col = nt + fj * 16 + lr;
            #pragma unroll
            for (int i = 0; i < 8; ++i) {
                short h_, lo_;
                split_bf16(W[(size_t)(h0 + i) * D_HIDDEN + col], h_, lo_);
                bh[fj][i] = h_; bl[fj][i] = lo_;
            }
        }
        #pragma unroll
        for (int fi = 0; fi < 2; ++fi)
            #pragma unroll
            for (int fj = 0; fj < 2; ++fj) {
                acc[fi][fj] = __builtin_amdgcn_mfma_f32_16x16x32_bf16(
                    ah[fi], bh[fj], acc[fi][fj], 0, 0, 0);
                acc[fi][fj] = __builtin_amdgcn_mfma_f32_16x16x32_bf16(
                    ah[fi], bl[fj], acc[fi][fj], 0, 0, 0);
                acc[fi][fj] = __builtin_amdgcn_mfma_f32_16x16x32_bf16(
                    al[fi], bh[fj], acc[fi][fj], 0, 0, 0);
            }
    }

    #pragma unroll
    for (int fi = 0; fi < 2; ++fi)
        #pragma unroll
        for (int fj = 0; fj < 2; ++fj)
            #pragma unroll
            for (int j = 0; j < 4; ++j) {
                const int row = mt + fi * 16 + (l >> 4) * 4 + j;
                const int col = nt + fj * 16 + lr;
                float pre = acc[fi][fj][j] + bias[col];
                if (fabsf(pre) < 3e-4f) {
                    unsigned idx = atomicAdd(&tcnt, 1u);
                    if (idx < TRIGCAP) {
                        tlist[idx] = ((unsigned)row << 11) | (unsigned)col;
                    } else {
                        const float* xr = x + (size_t)row * D_MODEL;
                        const float* wc = W + col;
                        double s = (double)bias[col];
                        for (int dd = 0; dd < D_MODEL; ++dd)
                            s += (double)xr[dd] * (double)wc[(size_t)dd * D_HIDDEN];
                        pre = (float)s;
                    }
                }
                outbuf[(size_t)row * D_HIDDEN + col] = fmaxf(pre, 0.f);
            }

    __syncthreads();
    const unsigned n = min(tcnt, (unsigned)TRIGCAP);
    for (unsigned i = 0; i < n; ++i) {
        const unsigned e = tlist[i];
        const int hh = (int)(e & 2047u);
        const int mm = (int)(e >> 11);
        double s = 0.0;
        #pragma unroll
        for (int k = 0; k < 3; ++k) {
            const int dd = t + k * 256;
            s += (double)x[(size_t)mm * D_MODEL + dd]
               * (double)W[(size_t)dd * D_HIDDEN + hh];
        }
        #pragma unroll
        for (int off = 32; off > 0; off >>= 1) s += __shfl_down(s, off);
        if (l == 0) redd[w] = s;
        __syncthreads();
        if (t == 0) {
            double tot = redd[0] + redd[1] + redd[2] + redd[3] + (double)bias[hh];
            outbuf[(size_t)mm * D_HIDDEN + hh] = fmaxf((float)tot, 0.f);
        }
        __syncthreads();
    }
}

// ---------------------------------------------------------------------------
// Kernel 1c: prep. Blocks [0,512): sign masks (R13-proven layout).
// Blocks [512,640): column sums for factorized reg:
//   sq[b*2048+h] += sum over 8 rows of sqrt(q[r,h]); nzq += count(q>0).
// (2 bufs x 4 batches x 16 rowgroups = 128 colsum blocks; fp atomics, ~ulp
// nondeterminism only -- reg tolerance is 2%.)
// ---------------------------------------------------------------------------
__global__ __launch_bounds__(256) void prep_kernel(
    const float* __restrict__ qbuf, const float* __restrict__ kbuf,
    unsigned* __restrict__ qmask, unsigned* __restrict__ kmask,
    float* __restrict__ sq, float* __restrict__ sk,
    float* __restrict__ nzq, float* __restrict__ nzk)
{
    const int bi = blockIdx.x;
    const int t  = threadIdx.x;

    if (bi < MROWS) {
        // ------------------------------ masks ------------------------------
        if (t >= 128) return;
        const int r = bi;
        const int l = t & 63;
        const float* src = (t < 64) ? qbuf : kbuf;
        unsigned* dst    = (t < 64) ? qmask : kmask;
        unsigned m = 0;
        #pragma unroll
        for (int j = 0; j < 8; ++j)
            #pragma unroll
            for (int e = 0; e < 4; ++e) {
                const float v = src[(size_t)r * D_HIDDEN + 256 * j + 4 * l + e];
                m |= (v > 0.f ? 1u : 0u) << (4 * j + e);
            }
        dst[r * 64 + l] = m;
        return;
    }

    // ------------------------------ colsums ------------------------------
    const int cid = bi - MROWS;            // 0..127
    const int buf = cid >> 6;              // 0: q, 1: k
    const int idx = cid & 63;
    const int b   = idx >> 4;
    const int rg  = idx & 15;
    const float* src = buf ? kbuf : qbuf;
    float* S  = buf ? sk  : sq;
    float* NZ = buf ? nzk : nzq;

    const int h0 = t * 8;
    float s[8]  = {0, 0, 0, 0, 0, 0, 0, 0};
    float nz[8] = {0, 0, 0, 0, 0, 0, 0, 0};
    #pragma unroll
    for (int rr = 0; rr < 8; ++rr) {
        const int row = b * SEQ + rg * 8 + rr;
        const float* p = src + (size_t)row * D_HIDDEN + h0;
        const f32x4 v1 = *reinterpret_cast<const f32x4*>(p);
        const f32x4 v2 = *reinterpret_cast<const f32x4*>(p + 4);
        #pragma unroll
        for (int e = 0; e < 4; ++e) {
            s[e]      += fsqrt_fast(v1[e]);
            nz[e]     += (v1[e] > 0.f) ? 1.f : 0.f;
            s[e + 4]  += fsqrt_fast(v2[e]);
            nz[e + 4] += (v2[e] > 0.f) ? 1.f : 0.f;
        }
    }
    #pragma unroll
    for (int e = 0; e < 8; ++e) {
        atomicAdd(&S[b * D_HIDDEN + h0 + e], s[e]);
        atomicAdd(&NZ[b * D_HIDDEN + h0 + e], nz[e]);
    }
}

// ---------------------------------------------------------------------------
// Kernel 2: fires [0,512) + score [512,1280) + finalize (block 1280).
//
// Fires: mask-driven pure store stream (R13-proven correctness) with NT
// stores (R10/R11 A/B: +10us vs cached). Per step: 1 dword load + bit
// expand + 8 NT f32x4 stores. Dense moving front; -1-shifted alignment;
// R==0 corner split to scalars (never touches out[REG_OFF]).
//
// Finalize: reg = 1e-3 * sum_{b,h} [ Sq*Sk + (16384 - nzq*nzk)*1e-3 ]
// (factorized sqrt: exact for zero products, ~1e-6-relative approx else).
// ---------------------------------------------------------------------------
__global__ __launch_bounds__(256) void main_kernel(
    const float* __restrict__ qbuf, const float* __restrict__ kbuf,
    const unsigned* __restrict__ qmask, const unsigned* __restrict__ kmask,
    const float* __restrict__ sq, const float* __restrict__ sk,
    const float* __restrict__ nzq, const float* __restrict__ nzk,
    const float* __restrict__ Wdec, const float* __restrict__ bdec,
    float* __restrict__ out)
{
    __shared__ float wcol[D_HIDDEN];
    __shared__ float red[4][64][16];
    const int t  = threadIdx.x;
    const int bi = blockIdx.x;
    const int w  = t >> 6;
    const int l  = t & 63;

    if (bi < FIRES_BLOCKS) {
        // ------------------------------ fires ------------------------------
        const int g  = bi * 4 + w;                         // 0..2047
        const int g7 = g >> 7;                             // 0..15
        const int gk = g & 127;

        f32x4* out4 = reinterpret_cast<f32x4*>(out + FIRES_OFF - 1);

        #pragma unroll 1
        for (int b = 0; b < 4; ++b) {
            const unsigned km = kmask[(b * SEQ + gk) * 64 + l];

            #pragma unroll 1
            for (int ss = 0; ss < 8; ++ss) {
                const int s    = b * 8 + ss;
                const int R    = g + s * FIRES_WAVES;
                const int brow = s * 16 + g7;              // R >> 7
                const unsigned qm = qmask[brow * 64 + l];
                const unsigned m   = qm & km;
                const unsigned mp  = __shfl_up(m, 1);
                const unsigned m63 = __shfl(m, 63);

                unsigned pb1 = 0;
                if (l == 0 && R > 0) {
                    const int pbrow = (R - 1) >> 7;
                    const int pb    = pbrow >> 7;
                    const int pkrow = (pb << 7) + ((R - 1) & 127);
                    pb1 = (qmask[pbrow * 64 + 63] >> 31)
                        & (kmask[pkrow * 64 + 63] >> 31) & 1u;
                }

                #pragma unroll
                for (int j = 0; j < 8; ++j) {
                    unsigned b0;
                    if (l == 0) b0 = (j == 0) ? pb1 : (m63 >> (4 * (j - 1) + 3)) & 1u;
                    else        b0 = (mp >> (4 * j + 3)) & 1u;
                    f32x4 f;
                    f[0] = b0 ? 1.f : 0.f;
                    f[1] = ((m >> (4 * j + 0)) & 1u) ? 1.f : 0.f;
                    f[2] = ((m >> (4 * j + 1)) & 1u) ? 1.f : 0.f;
                    f[3] = ((m >> (4 * j + 2)) & 1u) ? 1.f : 0.f;
                    if (R == 0 && j == 0 && l == 0) {
                        out[FIRES_OFF + 0] = f[1];
                        out[FIRES_OFF + 1] = f[2];
                        out[FIRES_OFF + 2] = f[3];
                    } else {
                        __builtin_nontemporal_store(f, &out4[(size_t)R * 512 + 64 * j + l]);
                    }
                }
            }
        }

        if (bi == FIRES_BLOCKS - 1 && w == 3 && l == 0) {
            const float pv = qbuf[(size_t)511 * D_HIDDEN + 2047]
                           * kbuf[(size_t)511 * D_HIDDEN + 2047];
            out[(size_t)(FIRES_OFF - 1) + (size_t)NROWS_T * D_HIDDEN] = (pv > 0.f) ? 1.f : 0.f;
        }
        return;
    }

    if (bi < FIRES_BLOCKS + SCORE_BLOCKS) {
        // ------------------------------ score ------------------------------
        const int sb  = bi - FIRES_BLOCKS;
        const int sub = sb & 15;
        const int pr  = sb >> 4;
        const int n   = pr % NHEADS;
        const int b   = pr / NHEADS;

        for (int idx = t; idx < D_HIDDEN; idx += 256)
            wcol[idx] = Wdec[(size_t)idx * NHEADS + n];
        __syncthreads();

        const int qt   = (sub >> 2) * 32;
        const int kt   = (sub & 3) * 32;
        const int lrow = l & 15;
        const int koff = (l >> 4) * 8;

        f32x4 acc[2][2];
        #pragma unroll
        for (int i = 0; i < 2; ++i)
            #pragma unroll
            for (int j = 0; j < 2; ++j) { f32x4 z = {0.f, 0.f, 0.f, 0.f}; acc[i][j] = z; }

        const float* qb = qbuf + (size_t)b * SEQ * D_HIDDEN;
        const float* kb = kbuf + (size_t)b * SEQ * D_HIDDEN;

        const int hlo = w * 512;
        for (int kk = hlo; kk < hlo + 512; kk += 32) {
            const int h0 = kk + koff;
            float wv[8];
            #pragma unroll
            for (int i = 0; i < 8; ++i) wv[i] = wcol[h0 + i];

            bf16x8 afrag[2], bfrag[2];
            #pragma unroll
            for (int fi = 0; fi < 2; ++fi) {
                const float* qp = qb + (size_t)(qt + fi * 16 + lrow) * D_HIDDEN + h0;
                const float4 q1 = *reinterpret_cast<const float4*>(qp);
                const float4 q2 = *reinterpret_cast<const float4*>(qp + 4);
                const float qf[8] = {q1.x, q1.y, q1.z, q1.w, q2.x, q2.y, q2.z, q2.w};
                #pragma unroll
                for (int i = 0; i < 8; ++i) afrag[fi][i] = (short)f2bf(qf[i] * wv[i]);
            }
            #pragma unroll
            for (int fj = 0; fj < 2; ++fj) {
                const float* kp = kb + (size_t)(kt + fj * 16 + lrow) * D_HIDDEN + h0;
                const float4 k1 = *reinterpret_cast<const float4*>(kp);
                const float4 k2 = *reinterpret_cast<const float4*>(kp + 4);
                const float kf[8] = {k1.x, k1.y, k1.z, k1.w, k2.x, k2.y, k2.z, k2.w};
                #pragma unroll
                for (int i = 0; i < 8; ++i) bfrag[fj][i] = (short)f2bf(kf[i]);
            }
            #pragma unroll
            for (int fi = 0; fi < 2; ++fi)
                #pragma unroll
                for (int fj = 0; fj < 2; ++fj)
                    acc[fi][fj] = __builtin_amdgcn_mfma_f32_16x16x32_bf16(
                        afrag[fi], bfrag[fj], acc[fi][fj], 0, 0, 0);
        }

        #pragma unroll
        for (int fi = 0; fi < 2; ++fi)
            #pragma unroll
            for (int fj = 0; fj < 2; ++fj)
                #pragma unroll
                for (int j = 0; j < 4; ++j)
                    red[w][l][fi * 8 + fj * 4 + j] = acc[fi][fj][j];
        __syncthreads();

        const float bd   = bdec[n];
        const int   outb = (b * NHEADS + n) * SEQ * SEQ;
        #pragma unroll
        for (int u = 0; u < 4; ++u) {
            const int j = w * 4 + u;
            const float s = (red[0][l][j] + red[1][l][j])
                          + (red[2][l][j] + red[3][l][j]);
            const int fi = j >> 3, fj = (j >> 2) & 1, jj = j & 3;
            const int row = qt + fi * 16 + (l >> 4) * 4 + jj;
            const int col = kt + fj * 16 + (l & 15);
            out[outb + row * SEQ + col] = s * 0.125f + bd;
        }
        return;
    }

    // ------------------------------ finalize ------------------------------
    {
        __shared__ double rd[4];
        double acc = 0.0;
        for (int i = t; i < BATCH * D_HIDDEN; i += 256) {
            const float zc = 16384.f - nzq[i] * nzk[i];
            acc += (double)(sq[i] * sk[i] + zc * 1e-3f);
        }
        #pragma unroll
        for (int off = 32; off > 0; off >>= 1) acc += __shfl_down(acc, off);
        if (l == 0) rd[w] = acc;
        __syncthreads();
        if (t == 0)
            out[REG_OFF] = (float)((rd[0] + rd[1] + rd[2] + rd[3]) * 1e-3);
    }
}

// ---------------------------------------------------------------------------
extern "C" void kernel_launch(void* const* d_in, const int* in_sizes, int n_in,
                              void* d_out, int out_size, void* d_ws, size_t ws_size,
                              hipStream_t stream) {
    const float* x  = (const float*)d_in[0];
    const float* WQ = (const float*)d_in[1];
    const float* WK = (const float*)d_in[2];
    const float* bQ = (const float*)d_in[3];
    const float* bK = (const float*)d_in[4];
    const float* Wd = (const float*)d_in[5];
    const float* bd = (const float*)d_in[6];
    float* out  = (float*)d_out;
    float* qbuf = (float*)d_ws;                                      // 4 MB
    float* kbuf = qbuf + (size_t)MROWS * D_HIDDEN;                   // 4 MB
    unsigned* qmask = (unsigned*)(kbuf + (size_t)MROWS * D_HIDDEN);  // 128 KB
    unsigned* kmask = qmask + (size_t)MROWS * 64;                    // 128 KB
    float* sq  = (float*)(kmask + (size_t)MROWS * 64);               // 32 KB
    float* sk  = sq  + BATCH * D_HIDDEN;
    float* nzq = sk  + BATCH * D_HIDDEN;
    float* nzk = nzq + BATCH * D_HIDDEN;

    dim3 b256(256);

    (void)hipMemsetAsync(sq, 0, (size_t)4 * BATCH * D_HIDDEN * sizeof(float), stream);

    enc_kernel<<<dim3(D_HIDDEN / 64, MROWS / 64, 2), b256, 0, stream>>>(
        x, WQ, WK, bQ, bK, qbuf, kbuf);

    prep_kernel<<<dim3(MROWS + 128), b256, 0, stream>>>(
        qbuf, kbuf, qmask, kmask, sq, sk, nzq, nzk);

    main_kernel<<<dim3(FIRES_BLOCKS + SCORE_BLOCKS + 1), b256, 0, stream>>>(
        qbuf, kbuf, qmask, kmask, sq, sk, nzq, nzk, Wd, bd, out);
}

// Round 15
// 169.955 us; speedup vs baseline: 1.1580x; 1.0079x over previous
//
#include <hip/hip_runtime.h>
#include <hip/hip_bf16.h>

#define D_MODEL 768
#define D_HIDDEN 2048
#define NHEADS 12
#define BATCH 4
#define SEQ 128
#define MROWS (BATCH*SEQ)                      // 512
#define SCORE_ELEMS (BATCH*NHEADS*SEQ*SEQ)     // 786432
#define REG_OFF SCORE_ELEMS
#define FIRES_OFF (SCORE_ELEMS + 1)
#define NROWS_T 65536
#define FIRES_WAVES 2048
#define FIRES_BLOCKS 512
#define SCORE_BLOCKS (BATCH*NHEADS*16)         // 768
#define TRIGCAP 64

typedef __attribute__((ext_vector_type(8))) short bf16x8;
typedef __attribute__((ext_vector_type(4))) short bf16x4;
typedef __attribute__((ext_vector_type(4))) float f32x4;

static __device__ __forceinline__ unsigned short f2bf(float f) {
    union { float f; unsigned u; } v; v.f = f;
    unsigned u = v.u;
    return (unsigned short)((u + 0x7FFFu + ((u >> 16) & 1u)) >> 16);  // RNE
}

static __device__ __forceinline__ void split_bf16(float v, short& hi, short& lo) {
    unsigned short h = f2bf(v);
    float hf = __uint_as_float((unsigned)h << 16);
    float lf = v - hf;
    hi = (short)h;
    lo = (short)f2bf(lf);
}

static __device__ __forceinline__ float fsqrt_fast(float x) {
    return __builtin_amdgcn_sqrtf(x);
}

// ---------------------------------------------------------------------------
// Kernel 0: pre-split planes. Blocks [0,768): W transpose+split (64x64 tiles,
// 12 h-tiles x 32 n-tiles x 2 matrices); WT planes are [2048][768] bf16.
// Blocks [768, 800): x split (row-major, no transpose), grid-stride.
// ---------------------------------------------------------------------------
__global__ __launch_bounds__(256) void prep_split_kernel(
    const float* __restrict__ x,
    const float* __restrict__ WQ, const float* __restrict__ WK,
    unsigned short* __restrict__ xh, unsigned short* __restrict__ xl,
    unsigned short* __restrict__ WQhT, unsigned short* __restrict__ WQlT,
    unsigned short* __restrict__ WKhT, unsigned short* __restrict__ WKlT)
{
    const int bi = blockIdx.x;
    const int t  = threadIdx.x;

    if (bi < 768) {
        __shared__ float tile[64][68];
        const int wz  = bi / 384;
        const int rem = bi % 384;
        const int h0  = (rem % 12) * 64;
        const int n0  = (rem / 12) * 64;
        const float* W = wz ? WK : WQ;
        unsigned short* dh = wz ? WKhT : WQhT;
        unsigned short* dl = wz ? WKlT : WQlT;

        #pragma unroll
        for (int u = 0; u < 4; ++u) {
            const int fid = t + 256 * u;
            const int h   = fid >> 4;
            const int c4  = (fid & 15) * 4;
            *reinterpret_cast<f32x4*>(&tile[h][c4]) =
                *reinterpret_cast<const f32x4*>(&W[(size_t)(h0 + h) * D_HIDDEN + n0 + c4]);
        }
        __syncthreads();
        #pragma unroll
        for (int u = 0; u < 4; ++u) {
            const int fid = t + 256 * u;
            const int n   = fid >> 4;
            const int h4  = (fid & 15) * 4;
            bf16x4 vh, vl;
            #pragma unroll
            for (int e = 0; e < 4; ++e) {
                short hh, ll;
                split_bf16(tile[h4 + e][n], hh, ll);
                vh[e] = hh; vl[e] = ll;
            }
            const size_t o = (size_t)(n0 + n) * D_MODEL + h0 + h4;
            *reinterpret_cast<bf16x4*>(&dh[o]) = vh;
            *reinterpret_cast<bf16x4*>(&dl[o]) = vl;
        }
        return;
    }

    // x split: 98304 f32x4 slots over 32 blocks
    for (int fid = (bi - 768) * 256 + t; fid < (MROWS * D_MODEL) / 4; fid += 32 * 256) {
        const f32x4 v = *reinterpret_cast<const f32x4*>(&x[(size_t)fid * 4]);
        bf16x4 vh, vl;
        #pragma unroll
        for (int e = 0; e < 4; ++e) {
            short hh, ll;
            split_bf16(v[e], hh, ll);
            vh[e] = hh; vl[e] = ll;
        }
        *reinterpret_cast<bf16x4*>(&xh[(size_t)fid * 4]) = vh;
        *reinterpret_cast<bf16x4*>(&xl[(size_t)fid * 4]) = vl;
    }
}

// ---------------------------------------------------------------------------
// Kernel 1-FAST: encoder GEMM from pre-split planes. LDS-tiled double-bf16:
// stage 64x32 hi/lo tiles of x (row-major) and WT (n-major) -- all loads
// coalesced 8B, all fragment reads aligned b128, zero split VALU in loop.
// acc += xh*wh + xh*wl + xl*wh. Inline fp64 fix epilogue (original x, W).
// ---------------------------------------------------------------------------
__global__ __launch_bounds__(256) void enc_fast_kernel(
    const unsigned short* __restrict__ xh, const unsigned short* __restrict__ xl,
    const unsigned short* __restrict__ WQhT, const unsigned short* __restrict__ WQlT,
    const unsigned short* __restrict__ WKhT, const unsigned short* __restrict__ WKlT,
    const float* __restrict__ x,
    const float* __restrict__ WQ, const float* __restrict__ WK,
    const float* __restrict__ bQ, const float* __restrict__ bK,
    float* __restrict__ qbuf, float* __restrict__ kbuf)
{
    __shared__ short xsh[64][40], xsl[64][40];     // 5.1 KB each
    __shared__ short wsh[64][40], wsl[64][40];
    __shared__ unsigned tcnt;
    __shared__ unsigned tlist[TRIGCAP];
    __shared__ double   redd[4];

    const int bufid = blockIdx.z;
    const unsigned short* Wh = bufid ? WKhT : WQhT;
    const unsigned short* Wl = bufid ? WKlT : WQlT;
    const float* Wf   = bufid ? WK : WQ;
    const float* bias = bufid ? bK : bQ;
    float* outbuf     = bufid ? kbuf : qbuf;

    const int t  = threadIdx.x;
    if (t == 0) tcnt = 0u;

    const int w  = t >> 6;
    const int l  = t & 63;
    const int m0 = blockIdx.y * 64;
    const int n0 = blockIdx.x * 64;
    const int mt = (w >> 1) * 32;
    const int nt = (w & 1) * 32;
    const int lr = l & 15;
    const int hg = (l >> 4) * 8;

    f32x4 acc[2][2];
    #pragma unroll
    for (int i = 0; i < 2; ++i)
        #pragma unroll
        for (int j = 0; j < 2; ++j) { f32x4 z = {0.f, 0.f, 0.f, 0.f}; acc[i][j] = z; }

    for (int kk = 0; kk < D_MODEL; kk += 32) {
        __syncthreads();
        #pragma unroll
        for (int u = 0; u < 2; ++u) {
            const int fid = t + 256 * u;
            const int row = fid >> 3;
            const int c4  = (fid & 7) * 4;
            const size_t xo = (size_t)(m0 + row) * D_MODEL + kk + c4;
            *reinterpret_cast<bf16x4*>(&xsh[row][c4]) =
                *reinterpret_cast<const bf16x4*>(&xh[xo]);
            *reinterpret_cast<bf16x4*>(&xsl[row][c4]) =
                *reinterpret_cast<const bf16x4*>(&xl[xo]);
            const size_t wo = (size_t)(n0 + row) * D_MODEL + kk + c4;
            *reinterpret_cast<bf16x4*>(&wsh[row][c4]) =
                *reinterpret_cast<const bf16x4*>(&Wh[wo]);
            *reinterpret_cast<bf16x4*>(&wsl[row][c4]) =
                *reinterpret_cast<const bf16x4*>(&Wl[wo]);
        }
        __syncthreads();

        bf16x8 ah[2], al[2], bh[2], bl[2];
        #pragma unroll
        for (int fi = 0; fi < 2; ++fi) {
            ah[fi] = *reinterpret_cast<const bf16x8*>(&xsh[mt + fi * 16 + lr][hg]);
            al[fi] = *reinterpret_cast<const bf16x8*>(&xsl[mt + fi * 16 + lr][hg]);
        }
        #pragma unroll
        for (int fj = 0; fj < 2; ++fj) {
            bh[fj] = *reinterpret_cast<const bf16x8*>(&wsh[nt + fj * 16 + lr][hg]);
            bl[fj] = *reinterpret_cast<const bf16x8*>(&wsl[nt + fj * 16 + lr][hg]);
        }
        #pragma unroll
        for (int fi = 0; fi < 2; ++fi)
            #pragma unroll
            for (int fj = 0; fj < 2; ++fj) {
                acc[fi][fj] = __builtin_amdgcn_mfma_f32_16x16x32_bf16(
                    ah[fi], bh[fj], acc[fi][fj], 0, 0, 0);
                acc[fi][fj] = __builtin_amdgcn_mfma_f32_16x16x32_bf16(
                    ah[fi], bl[fj], acc[fi][fj], 0, 0, 0);
                acc[fi][fj] = __builtin_amdgcn_mfma_f32_16x16x32_bf16(
                    al[fi], bh[fj], acc[fi][fj], 0, 0, 0);
            }
    }

    #pragma unroll
    for (int fi = 0; fi < 2; ++fi)
        #pragma unroll
        for (int fj = 0; fj < 2; ++fj)
            #pragma unroll
            for (int j = 0; j < 4; ++j) {
                const int row = m0 + mt + fi * 16 + (l >> 4) * 4 + j;
                const int col = n0 + nt + fj * 16 + lr;
                float pre = acc[fi][fj][j] + bias[col];
                if (fabsf(pre) < 3e-4f) {
                    unsigned idx = atomicAdd(&tcnt, 1u);
                    if (idx < TRIGCAP) {
                        tlist[idx] = ((unsigned)row << 11) | (unsigned)col;
                    } else {
                        const float* xr = x + (size_t)row * D_MODEL;
                        const float* wc = Wf + col;
                        double s = (double)bias[col];
                        for (int dd = 0; dd < D_MODEL; ++dd)
                            s += (double)xr[dd] * (double)wc[(size_t)dd * D_HIDDEN];
                        pre = (float)s;
                    }
                }
                outbuf[(size_t)row * D_HIDDEN + col] = fmaxf(pre, 0.f);
            }

    __syncthreads();
    const unsigned n = min(tcnt, (unsigned)TRIGCAP);
    for (unsigned i = 0; i < n; ++i) {
        const unsigned e = tlist[i];
        const int hh = (int)(e & 2047u);
        const int mm = (int)(e >> 11);
        double s = 0.0;
        #pragma unroll
        for (int k = 0; k < 3; ++k) {
            const int dd = t + k * 256;
            s += (double)x[(size_t)mm * D_MODEL + dd]
               * (double)Wf[(size_t)dd * D_HIDDEN + hh];
        }
        #pragma unroll
        for (int off = 32; off > 0; off >>= 1) s += __shfl_down(s, off);
        if (l == 0) redd[w] = s;
        __syncthreads();
        if (t == 0) {
            double tot = redd[0] + redd[1] + redd[2] + redd[3] + (double)bias[hh];
            outbuf[(size_t)mm * D_HIDDEN + hh] = fmaxf((float)tot, 0.f);
        }
        __syncthreads();
    }
}

// ---------------------------------------------------------------------------
// Kernel 1-FALLBACK: R14 enc (split-bf16 from global), used if ws too small.
// ---------------------------------------------------------------------------
__global__ __launch_bounds__(256) void enc_kernel(
    const float* __restrict__ x,
    const float* __restrict__ WQ, const float* __restrict__ WK,
    const float* __restrict__ bQ, const float* __restrict__ bK,
    float* __restrict__ qbuf, float* __restrict__ kbuf)
{
    __shared__ unsigned tcnt;
    __shared__ unsigned tlist[TRIGCAP];
    __shared__ double   redd[4];

    const int bufid = blockIdx.z;
    const float* W    = bufid ? WK : WQ;
    const float* bias = bufid ? bK : bQ;
    float* outbuf     = bufid ? kbuf : qbuf;

    const int t  = threadIdx.x;
    if (t == 0) tcnt = 0u;
    __syncthreads();

    const int w  = t >> 6;
    const int l  = t & 63;
    const int mt = blockIdx.y * 64 + (w >> 1) * 32;
    const int nt = blockIdx.x * 64 + (w & 1) * 32;
    const int lr = l & 15;
    const int hg = (l >> 4) * 8;

    f32x4 acc[2][2];
    #pragma unroll
    for (int i = 0; i < 2; ++i)
        #pragma unroll
        for (int j = 0; j < 2; ++j) { f32x4 z = {0.f, 0.f, 0.f, 0.f}; acc[i][j] = z; }

    for (int kk = 0; kk < D_MODEL; kk += 32) {
        const int h0 = kk + hg;
        bf16x8 ah[2], al[2], bh[2], bl[2];
        #pragma unroll
        for (int fi = 0; fi < 2; ++fi) {
            const float* xp = x + (size_t)(mt + fi * 16 + lr) * D_MODEL + h0;
            const float4 v1 = *reinterpret_cast<const float4*>(xp);
            const float4 v2 = *reinterpret_cast<const float4*>(xp + 4);
            const float vv[8] = {v1.x, v1.y, v1.z, v1.w, v2.x, v2.y, v2.z, v2.w};
            #pragma unroll
            for (int i = 0; i < 8; ++i) {
                short h_, lo_;
                split_bf16(vv[i], h_, lo_);
                ah[fi][i] = h_; al[fi][i] = lo_;
            }
        }
        #pragma unroll
        for (int fj = 0; fj < 2; ++fj) {
            const int col = nt + fj * 16 + lr;
            #pragma unroll
            for (int i = 0; i < 8; ++i) {
                short h_, lo_;
                split_bf16(W[(size_t)(h0 + i) * D_HIDDEN + col], h_, lo_);
                bh[fj][i] = h_; bl[fj][i] = lo_;
            }
        }
        #pragma unroll
        for (int fi = 0; fi < 2; ++fi)
            #pragma unroll
            for (int fj = 0; fj < 2; ++fj) {
                acc[fi][fj] = __builtin_amdgcn_mfma_f32_16x16x32_bf16(
                    ah[fi], bh[fj], acc[fi][fj], 0, 0, 0);
                acc[fi][fj] = __builtin_amdgcn_mfma_f32_16x16x32_bf16(
                    ah[fi], bl[fj], acc[fi][fj], 0, 0, 0);
                acc[fi][fj] = __builtin_amdgcn_mfma_f32_16x16x32_bf16(
                    al[fi], bh[fj], acc[fi][fj], 0, 0, 0);
            }
    }

    #pragma unroll
    for (int fi = 0; fi < 2; ++fi)
        #pragma unroll
        for (int fj = 0; fj < 2; ++fj)
            #pragma unroll
            for (int j = 0; j < 4; ++j) {
                const int row = mt + fi * 16 + (l >> 4) * 4 + j;
                const int col = nt + fj * 16 + lr;
                float pre = acc[fi][fj][j] + bias[col];
                if (fabsf(pre) < 3e-4f) {
                    unsigned idx = atomicAdd(&tcnt, 1u);
                    if (idx < TRIGCAP) {
                        tlist[idx] = ((unsigned)row << 11) | (unsigned)col;
                    } else {
                        const float* xr = x + (size_t)row * D_MODEL;
                        const float* wc = W + col;
                        double s = (double)bias[col];
                        for (int dd = 0; dd < D_MODEL; ++dd)
                            s += (double)xr[dd] * (double)wc[(size_t)dd * D_HIDDEN];
                        pre = (float)s;
                    }
                }
                outbuf[(size_t)row * D_HIDDEN + col] = fmaxf(pre, 0.f);
            }

    __syncthreads();
    const unsigned n = min(tcnt, (unsigned)TRIGCAP);
    for (unsigned i = 0; i < n; ++i) {
        const unsigned e = tlist[i];
        const int hh = (int)(e & 2047u);
        const int mm = (int)(e >> 11);
        double s = 0.0;
        #pragma unroll
        for (int k = 0; k < 3; ++k) {
            const int dd = t + k * 256;
            s += (double)x[(size_t)mm * D_MODEL + dd]
               * (double)W[(size_t)dd * D_HIDDEN + hh];
        }
        #pragma unroll
        for (int off = 32; off > 0; off >>= 1) s += __shfl_down(s, off);
        if (l == 0) redd[w] = s;
        __syncthreads();
        if (t == 0) {
            double tot = redd[0] + redd[1] + redd[2] + redd[3] + (double)bias[hh];
            outbuf[(size_t)mm * D_HIDDEN + hh] = fmaxf((float)tot, 0.f);
        }
        __syncthreads();
    }
}

// ---------------------------------------------------------------------------
// Kernel 1c: prep -- masks [0,512) + factorized-reg colsums [512,640).
// (unchanged R14, proven)
// ---------------------------------------------------------------------------
__global__ __launch_bounds__(256) void prep_kernel(
    const float* __restrict__ qbuf, const float* __restrict__ kbuf,
    unsigned* __restrict__ qmask, unsigned* __restrict__ kmask,
    float* __restrict__ sq, float* __restrict__ sk,
    float* __restrict__ nzq, float* __restrict__ nzk)
{
    const int bi = blockIdx.x;
    const int t  = threadIdx.x;

    if (bi < MROWS) {
        if (t >= 128) return;
        const int r = bi;
        const int l = t & 63;
        const float* src = (t < 64) ? qbuf : kbuf;
        unsigned* dst    = (t < 64) ? qmask : kmask;
        unsigned m = 0;
        #pragma unroll
        for (int j = 0; j < 8; ++j)
            #pragma unroll
            for (int e = 0; e < 4; ++e) {
                const float v = src[(size_t)r * D_HIDDEN + 256 * j + 4 * l + e];
                m |= (v > 0.f ? 1u : 0u) << (4 * j + e);
            }
        dst[r * 64 + l] = m;
        return;
    }

    const int cid = bi - MROWS;
    const int buf = cid >> 6;
    const int idx = cid & 63;
    const int b   = idx >> 4;
    const int rg  = idx & 15;
    const float* src = buf ? kbuf : qbuf;
    float* S  = buf ? sk  : sq;
    float* NZ = buf ? nzk : nzq;

    const int h0 = t * 8;
    float s[8]  = {0, 0, 0, 0, 0, 0, 0, 0};
    float nz[8] = {0, 0, 0, 0, 0, 0, 0, 0};
    #pragma unroll
    for (int rr = 0; rr < 8; ++rr) {
        const int row = b * SEQ + rg * 8 + rr;
        const float* p = src + (size_t)row * D_HIDDEN + h0;
        const f32x4 v1 = *reinterpret_cast<const f32x4*>(p);
        const f32x4 v2 = *reinterpret_cast<const f32x4*>(p + 4);
        #pragma unroll
        for (int e = 0; e < 4; ++e) {
            s[e]      += fsqrt_fast(v1[e]);
            nz[e]     += (v1[e] > 0.f) ? 1.f : 0.f;
            s[e + 4]  += fsqrt_fast(v2[e]);
            nz[e + 4] += (v2[e] > 0.f) ? 1.f : 0.f;
        }
    }
    #pragma unroll
    for (int e = 0; e < 8; ++e) {
        atomicAdd(&S[b * D_HIDDEN + h0 + e], s[e]);
        atomicAdd(&NZ[b * D_HIDDEN + h0 + e], nz[e]);
    }
}

// ---------------------------------------------------------------------------
// Kernel 2: fires [0,512) + score [512,1280) + finalize (block 1280).
// (unchanged R14, proven best)
// ---------------------------------------------------------------------------
__global__ __launch_bounds__(256) void main_kernel(
    const float* __restrict__ qbuf, const float* __restrict__ kbuf,
    const unsigned* __restrict__ qmask, const unsigned* __restrict__ kmask,
    const float* __restrict__ sq, const float* __restrict__ sk,
    const float* __restrict__ nzq, const float* __restrict__ nzk,
    const float* __restrict__ Wdec, const float* __restrict__ bdec,
    float* __restrict__ out)
{
    __shared__ float wcol[D_HIDDEN];
    __shared__ float red[4][64][16];
    const int t  = threadIdx.x;
    const int bi = blockIdx.x;
    const int w  = t >> 6;
    const int l  = t & 63;

    if (bi < FIRES_BLOCKS) {
        const int g  = bi * 4 + w;
        const int g7 = g >> 7;
        const int gk = g & 127;

        f32x4* out4 = reinterpret_cast<f32x4*>(out + FIRES_OFF - 1);

        #pragma unroll 1
        for (int b = 0; b < 4; ++b) {
            const unsigned km = kmask[(b * SEQ + gk) * 64 + l];

            #pragma unroll 1
            for (int ss = 0; ss < 8; ++ss) {
                const int s    = b * 8 + ss;
                const int R    = g + s * FIRES_WAVES;
                const int brow = s * 16 + g7;
                const unsigned qm = qmask[brow * 64 + l];
                const unsigned m   = qm & km;
                const unsigned mp  = __shfl_up(m, 1);
                const unsigned m63 = __shfl(m, 63);

                unsigned pb1 = 0;
                if (l == 0 && R > 0) {
                    const int pbrow = (R - 1) >> 7;
                    const int pb    = pbrow >> 7;
                    const int pkrow = (pb << 7) + ((R - 1) & 127);
                    pb1 = (qmask[pbrow * 64 + 63] >> 31)
                        & (kmask[pkrow * 64 + 63] >> 31) & 1u;
                }

                #pragma unroll
                for (int j = 0; j < 8; ++j) {
                    unsigned b0;
                    if (l == 0) b0 = (j == 0) ? pb1 : (m63 >> (4 * (j - 1) + 3)) & 1u;
                    else        b0 = (mp >> (4 * j + 3)) & 1u;
                    f32x4 f;
                    f[0] = b0 ? 1.f : 0.f;
                    f[1] = ((m >> (4 * j + 0)) & 1u) ? 1.f : 0.f;
                    f[2] = ((m >> (4 * j + 1)) & 1u) ? 1.f : 0.f;
                    f[3] = ((m >> (4 * j + 2)) & 1u) ? 1.f : 0.f;
                    if (R == 0 && j == 0 && l == 0) {
                        out[FIRES_OFF + 0] = f[1];
                        out[FIRES_OFF + 1] = f[2];
                        out[FIRES_OFF + 2] = f[3];
                    } else {
                        __builtin_nontemporal_store(f, &out4[(size_t)R * 512 + 64 * j + l]);
                    }
                }
            }
        }

        if (bi == FIRES_BLOCKS - 1 && w == 3 && l == 0) {
            const float pv = qbuf[(size_t)511 * D_HIDDEN + 2047]
                           * kbuf[(size_t)511 * D_HIDDEN + 2047];
            out[(size_t)(FIRES_OFF - 1) + (size_t)NROWS_T * D_HIDDEN] = (pv > 0.f) ? 1.f : 0.f;
        }
        return;
    }

    if (bi < FIRES_BLOCKS + SCORE_BLOCKS) {
        const int sb  = bi - FIRES_BLOCKS;
        const int sub = sb & 15;
        const int pr  = sb >> 4;
        const int n   = pr % NHEADS;
        const int b   = pr / NHEADS;

        for (int idx = t; idx < D_HIDDEN; idx += 256)
            wcol[idx] = Wdec[(size_t)idx * NHEADS + n];
        __syncthreads();

        const int qt   = (sub >> 2) * 32;
        const int kt   = (sub & 3) * 32;
        const int lrow = l & 15;
        const int koff = (l >> 4) * 8;

        f32x4 acc[2][2];
        #pragma unroll
        for (int i = 0; i < 2; ++i)
            #pragma unroll
            for (int j = 0; j < 2; ++j) { f32x4 z = {0.f, 0.f, 0.f, 0.f}; acc[i][j] = z; }

        const float* qb = qbuf + (size_t)b * SEQ * D_HIDDEN;
        const float* kb = kbuf + (size_t)b * SEQ * D_HIDDEN;

        const int hlo = w * 512;
        for (int kk = hlo; kk < hlo + 512; kk += 32) {
            const int h0 = kk + koff;
            float wv[8];
            #pragma unroll
            for (int i = 0; i < 8; ++i) wv[i] = wcol[h0 + i];

            bf16x8 afrag[2], bfrag[2];
            #pragma unroll
            for (int fi = 0; fi < 2; ++fi) {
                const float* qp = qb + (size_t)(qt + fi * 16 + lrow) * D_HIDDEN + h0;
                const float4 q1 = *reinterpret_cast<const float4*>(qp);
                const float4 q2 = *reinterpret_cast<const float4*>(qp + 4);
                const float qf[8] = {q1.x, q1.y, q1.z, q1.w, q2.x, q2.y, q2.z, q2.w};
                #pragma unroll
                for (int i = 0; i < 8; ++i) afrag[fi][i] = (short)f2bf(qf[i] * wv[i]);
            }
            #pragma unroll
            for (int fj = 0; fj < 2; ++fj) {
                const float* kp = kb + (size_t)(kt + fj * 16 + lrow) * D_HIDDEN + h0;
                const float4 k1 = *reinterpret_cast<const float4*>(kp);
                const float4 k2 = *reinterpret_cast<const float4*>(kp + 4);
                const float kf[8] = {k1.x, k1.y, k1.z, k1.w, k2.x, k2.y, k2.z, k2.w};
                #pragma unroll
                for (int i = 0; i < 8; ++i) bfrag[fj][i] = (short)f2bf(kf[i]);
            }
            #pragma unroll
            for (int fi = 0; fi < 2; ++fi)
                #pragma unroll
                for (int fj = 0; fj < 2; ++fj)
                    acc[fi][fj] = __builtin_amdgcn_mfma_f32_16x16x32_bf16(
                        afrag[fi], bfrag[fj], acc[fi][fj], 0, 0, 0);
        }

        #pragma unroll
        for (int fi = 0; fi < 2; ++fi)
            #pragma unroll
            for (int fj = 0; fj < 2; ++fj)
                #pragma unroll
                for (int j = 0; j < 4; ++j)
                    red[w][l][fi * 8 + fj * 4 + j] = acc[fi][fj][j];
        __syncthreads();

        const float bd   = bdec[n];
        const int   outb = (b * NHEADS + n) * SEQ * SEQ;
        #pragma unroll
        for (int u = 0; u < 4; ++u) {
            const int j = w * 4 + u;
            const float s = (red[0][l][j] + red[1][l][j])
                          + (red[2][l][j] + red[3][l][j]);
            const int fi = j >> 3, fj = (j >> 2) & 1, jj = j & 3;
            const int row = qt + fi * 16 + (l >> 4) * 4 + jj;
            const int col = kt + fj * 16 + (l & 15);
            out[outb + row * SEQ + col] = s * 0.125f + bd;
        }
        return;
    }

    {
        __shared__ double rd[4];
        double acc = 0.0;
        for (int i = t; i < BATCH * D_HIDDEN; i += 256) {
            const float zc = 16384.f - nzq[i] * nzk[i];
            acc += (double)(sq[i] * sk[i] + zc * 1e-3f);
        }
        #pragma unroll
        for (int off = 32; off > 0; off >>= 1) acc += __shfl_down(acc, off);
        if (l == 0) rd[w] = acc;
        __syncthreads();
        if (t == 0)
            out[REG_OFF] = (float)((rd[0] + rd[1] + rd[2] + rd[3]) * 1e-3);
    }
}

// ---------------------------------------------------------------------------
extern "C" void kernel_launch(void* const* d_in, const int* in_sizes, int n_in,
                              void* d_out, int out_size, void* d_ws, size_t ws_size,
                              hipStream_t stream) {
    const float* x  = (const float*)d_in[0];
    const float* WQ = (const float*)d_in[1];
    const float* WK = (const float*)d_in[2];
    const float* bQ = (const float*)d_in[3];
    const float* bK = (const float*)d_in[4];
    const float* Wd = (const float*)d_in[5];
    const float* bd = (const float*)d_in[6];
    float* out  = (float*)d_out;

    char* p = (char*)d_ws;
    float* qbuf = (float*)p;             p += (size_t)MROWS * D_HIDDEN * 4;
    float* kbuf = (float*)p;             p += (size_t)MROWS * D_HIDDEN * 4;
    unsigned* qmask = (unsigned*)p;      p += (size_t)MROWS * 64 * 4;
    unsigned* kmask = (unsigned*)p;      p += (size_t)MROWS * 64 * 4;
    float* sq  = (float*)p;              p += BATCH * D_HIDDEN * 4;
    float* sk  = (float*)p;              p += BATCH * D_HIDDEN * 4;
    float* nzq = (float*)p;              p += BATCH * D_HIDDEN * 4;
    float* nzk = (float*)p;              p += BATCH * D_HIDDEN * 4;
    unsigned short* xh   = (unsigned short*)p; p += (size_t)MROWS * D_MODEL * 2;
    unsigned short* xl   = (unsigned short*)p; p += (size_t)MROWS * D_MODEL * 2;
    unsigned short* WQhT = (unsigned short*)p; p += (size_t)D_HIDDEN * D_MODEL * 2;
    unsigned short* WQlT = (unsigned short*)p; p += (size_t)D_HIDDEN * D_MODEL * 2;
    unsigned short* WKhT = (unsigned short*)p; p += (size_t)D_HIDDEN * D_MODEL * 2;
    unsigned short* WKlT = (unsigned short*)p; p += (size_t)D_HIDDEN * D_MODEL * 2;
    const size_t need_full = (size_t)(p - (char*)d_ws);
    const bool fast = (ws_size >= need_full);

    dim3 b256(256);

    (void)hipMemsetAsync(sq, 0, (size_t)4 * BATCH * D_HIDDEN * sizeof(float), stream);

    if (fast) {
        prep_split_kernel<<<dim3(800), b256, 0, stream>>>(
            x, WQ, WK, xh, xl, WQhT, WQlT, WKhT, WKlT);
        enc_fast_kernel<<<dim3(D_HIDDEN / 64, MROWS / 64, 2), b256, 0, stream>>>(
            xh, xl, WQhT, WQlT, WKhT, WKlT, x, WQ, WK, bQ, bK, qbuf, kbuf);
    } else {
        enc_kernel<<<dim3(D_HIDDEN / 64, MROWS / 64, 2), b256, 0, stream>>>(
            x, WQ, WK, bQ, bK, qbuf, kbuf);
    }

    prep_kernel<<<dim3(MROWS + 128), b256, 0, stream>>>(
        qbuf, kbuf, qmask, kmask, sq, sk, nzq, nzk);

    main_kernel<<<dim3(FIRES_BLOCKS + SCORE_BLOCKS + 1), b256, 0, stream>>>(
        qbuf, kbuf, qmask, kmask, sq, sk, nzq, nzk, Wd, bd, out);
}